// Round 4
// baseline (817.748 us; speedup 1.0000x reference)
//
#include <hip/hip_runtime.h>
#include <math.h>

#define NUM_I 100
#define NZ    16
#define NCAND (NUM_I * NZ)
#define NBC   4096            // coarse bins
#define NBF   32768           // fine bins = NBC * 8
#define F32_EPS 1.1920928955078125e-07f

#define AGENT __HIP_MEMORY_SCOPE_AGENT

static __device__ __forceinline__ unsigned agent_load_u32(const unsigned* p) {
    return __hip_atomic_load(p, __ATOMIC_RELAXED, AGENT);
}
static __device__ __forceinline__ float agent_load_f32(const float* p) {
    return __hip_atomic_load(p, __ATOMIC_RELAXED, AGENT);
}
static __device__ __forceinline__ double agent_load_f64(const double* p) {
    return __hip_atomic_load(p, __ATOMIC_RELAXED, AGENT);
}
static __device__ __forceinline__ void agent_store_f32(float* p, float v) {
    __hip_atomic_store(p, v, __ATOMIC_RELAXED, AGENT);
}
static __device__ __forceinline__ void agent_store_f64(double* p, double v) {
    __hip_atomic_store(p, v, __ATOMIC_RELAXED, AGENT);
}
static __device__ __forceinline__ float rfl_f(float v) {
    return __int_as_float(__builtin_amdgcn_readfirstlane(__float_as_int(v)));
}

// global monotone value->fine-bin map. Coarse bin is ALWAYS fine>>3 (exact since
// invw is shared), so all kernels agree on membership by construction.
static __device__ __forceinline__ int bin_fine(float v, float lo, float invw) {
    int f = (int)floorf((v - lo) * invw);
    return min(max(f, 0), NBF - 1);
}

// ============ K1: min/max partials + last-block finalize + candidate params ============
__global__ __launch_bounds__(256) void k_minmax_setup(const float* __restrict__ x, int n4,
                                                      float* pmin, float* pmax,
                                                      unsigned* ctr,
                                                      float4* params, float2* ranges,
                                                      float* mm) {
#pragma clang fp contract(off)
    __shared__ float rmin[256], rmax[256];
    __shared__ int islast;
    int tid = threadIdx.x;
    int gtid = blockIdx.x * 256 + tid;
    int stride = gridDim.x * 256;
    const float4* x4 = (const float4*)x;
    float lmin = 3.0e38f, lmax = -3.0e38f;
    for (int i = gtid; i < n4; i += stride) {
        float4 v = x4[i];
        lmin = fminf(lmin, fminf(fminf(v.x, v.y), fminf(v.z, v.w)));
        lmax = fmaxf(lmax, fmaxf(fmaxf(v.x, v.y), fmaxf(v.z, v.w)));
    }
    rmin[tid] = lmin; rmax[tid] = lmax;
    __syncthreads();
    for (int s = 128; s > 0; s >>= 1) {
        if (tid < s) {
            rmin[tid] = fminf(rmin[tid], rmin[tid + s]);
            rmax[tid] = fmaxf(rmax[tid], rmax[tid + s]);
        }
        __syncthreads();
    }
    if (tid == 0) {
        agent_store_f32(&pmin[blockIdx.x], rmin[0]);
        agent_store_f32(&pmax[blockIdx.x], rmax[0]);
        __threadfence();
        unsigned old = atomicAdd(ctr, 1u);
        islast = (old == gridDim.x - 1) ? 1 : 0;
    }
    __syncthreads();
    if (!islast) return;
    __threadfence();

    // last block: final reduce over all partials (agent loads bypass stale caches)
    lmin = 3.0e38f; lmax = -3.0e38f;
    for (int i = tid; i < (int)gridDim.x; i += 256) {
        lmin = fminf(lmin, agent_load_f32(&pmin[i]));
        lmax = fmaxf(lmax, agent_load_f32(&pmax[i]));
    }
    rmin[tid] = lmin; rmax[tid] = lmax;
    __syncthreads();
    for (int s = 128; s > 0; s >>= 1) {
        if (tid < s) {
            rmin[tid] = fminf(rmin[tid], rmin[tid + s]);
            rmax[tid] = fmaxf(rmax[tid], rmax[tid + s]);
        }
        __syncthreads();
    }
    float x_min = rmin[0], x_max = rmax[0];
    if (tid == 0) {
        mm[0] = x_min; mm[1] = x_max;
        float range = x_max - x_min;
        mm[2] = x_min;                                          // lo
        mm[3] = (range > 0.0f) ? ((float)NBF / range) : 0.0f;   // fine invw
    }

    // candidate params (identical math to proven round-3 k_setup)
    float xrange = x_max - x_min;
    float step = xrange / 100.0f;
    for (int c = tid; c < NCAND; c += 256) {
        int ii = c >> 4;
        int z  = c & 15;
        float fi = (float)(ii + 1);
        float tmp_max   = step * fi;
        float tmp_delta = tmp_max / 15.0f;
        float t = (float)z * tmp_delta;
        float new_min = fmaxf(-t, x_min);
        float new_max = fminf(tmp_max - t, x_max);
        float min_neg = fminf(new_min, 0.0f);
        float max_pos = fmaxf(new_max, 0.0f);
        float scale = fmaxf((max_pos - min_neg) / 15.0f, F32_EPS);
        float zp = 0.0f - rintf(min_neg / scale);
        zp = fminf(fmaxf(zp, 0.0f), 15.0f);
        float inv = (float)(1.0 / (double)scale);
        params[c] = make_float4(scale, inv, 0.0f - zp, 15.0f - zp);
        ranges[c] = make_float2(new_min, new_max);
    }
}

// ============ K2: fused coarse hist + grid-spin + scan + scatter (grid=128, co-resident) ============
__global__ __launch_bounds__(256) void k_hist_scatter(const float* __restrict__ x, int n4,
                                                      const float* __restrict__ mm,
                                                      unsigned* hist, unsigned* cdelta,
                                                      unsigned* hdone,
                                                      unsigned* bin_start,
                                                      float* __restrict__ y1) {
    __shared__ unsigned lhist[NBC];    // this block's counts (kept for reservation)
    __shared__ unsigned lstart[NBC];   // global exclusive start -> then block cursor
    __shared__ unsigned lscan[256];
    __shared__ int lflag;
    int tid = threadIdx.x, nb = gridDim.x, b0 = blockIdx.x;
    for (int k = tid; k < NBC; k += 256) lhist[k] = 0u;
    __syncthreads();
    float lo = mm[2], invw = mm[3];
    const float4* x4 = (const float4*)x;
    int seg = (n4 + nb - 1) / nb;
    int beg = b0 * seg;
    int end = min(beg + seg, n4);
    // phase 1: local count (coarse = fine>>3 for global consistency)
    for (int i = beg + tid; i < end; i += 256) {
        float4 v = x4[i];
        atomicAdd(&lhist[bin_fine(v.x, lo, invw) >> 3], 1u);
        atomicAdd(&lhist[bin_fine(v.y, lo, invw) >> 3], 1u);
        atomicAdd(&lhist[bin_fine(v.z, lo, invw) >> 3], 1u);
        atomicAdd(&lhist[bin_fine(v.w, lo, invw) >> 3], 1u);
    }
    __syncthreads();
    // merge to global (no-return atomics)
    for (int k = tid; k < NBC; k += 256) {
        unsigned c = lhist[k];
        if (c) atomicAdd(&hist[k], c);
    }
    __threadfence();
    __syncthreads();
    // grid barrier: all 128 blocks are co-resident (LDS 33KB -> >=4 blk/CU, 128 <= 256 CUs)
    if (tid == 0) {
        atomicAdd(hdone, 1u);
        while (agent_load_u32(hdone) < (unsigned)nb) __builtin_amdgcn_s_sleep(8);
        lflag = 1;
    }
    __syncthreads();
    __threadfence();
    (void)lflag;
    // read full global hist, block-local exclusive scan
    unsigned gh[16];
    unsigned psum = 0;
    for (int k = 0; k < 16; k++) { gh[k] = agent_load_u32(&hist[tid * 16 + k]); psum += gh[k]; }
    lscan[tid] = psum;
    __syncthreads();
    for (int off = 1; off < 256; off <<= 1) {
        unsigned v = (tid >= off) ? lscan[tid - off] : 0u;
        __syncthreads();
        lscan[tid] += v;
        __syncthreads();
    }
    unsigned run = lscan[tid] - psum;   // exclusive
    for (int k = 0; k < 16; k++) { lstart[tid * 16 + k] = run; run += gh[k]; }
    if (b0 == 0) {
        for (int k = 0; k < 16; k++) bin_start[tid * 16 + k] = lstart[tid * 16 + k];
        if (tid == 255) bin_start[NBC] = run;
    }
    __syncthreads();
    // reserve per-block region in each bin (independent returning atomics, latency-overlapped)
    for (int k = 0; k < 16; k++) {
        int bb = tid * 16 + k;
        unsigned c = lhist[bb];
        if (c) { unsigned d = atomicAdd(&cdelta[bb], c); lstart[bb] += d; }
    }
    __syncthreads();
    // scatter via LDS cursors (re-read of segment is L2-hot)
    for (int i = beg + tid; i < end; i += 256) {
        float4 v = x4[i];
        unsigned p0 = atomicAdd(&lstart[bin_fine(v.x, lo, invw) >> 3], 1u); y1[p0] = v.x;
        unsigned p1 = atomicAdd(&lstart[bin_fine(v.y, lo, invw) >> 3], 1u); y1[p1] = v.y;
        unsigned p2 = atomicAdd(&lstart[bin_fine(v.z, lo, invw) >> 3], 1u); y1[p2] = v.z;
        unsigned p3 = atomicAdd(&lstart[bin_fine(v.w, lo, invw) >> 3], 1u); y1[p3] = v.w;
    }
}

// ============ K3: per-coarse-bin sub-scatter (8 fine) + fused binsums + last-block prefix ============
__global__ __launch_bounds__(256) void k_subscatter(const float* __restrict__ y1,
                                                    const unsigned* __restrict__ bin_start,
                                                    const float* __restrict__ mm,
                                                    float* __restrict__ y2,
                                                    unsigned* fstart,
                                                    double* bS1, double* bS2,
                                                    unsigned* ctr,
                                                    double* P1, double* P2) {
    __shared__ unsigned scnt[8], sstart[9], lcur[8];
    __shared__ unsigned wpart[8][4];
    __shared__ int islast;
    int tid = threadIdx.x, lane = tid & 63, w = tid >> 6;
    int b = blockIdx.x;
    unsigned beg = bin_start[b], end = bin_start[b + 1];
    float lo = mm[2], invw = mm[3];

    // phase A: VGPR-private sub-bin counts (no atomics)
    unsigned c[8] = {0,0,0,0,0,0,0,0};
    for (unsigned i = beg + tid; i < end; i += 256) {
        int sub = bin_fine(y1[i], lo, invw) & 7;
        #pragma unroll
        for (int j = 0; j < 8; j++) c[j] += (sub == j) ? 1u : 0u;
    }
    #pragma unroll
    for (int j = 0; j < 8; j++) {
        #pragma unroll
        for (int off = 32; off > 0; off >>= 1) c[j] += __shfl_xor(c[j], off);
    }
    if (lane == 0) {
        #pragma unroll
        for (int j = 0; j < 8; j++) wpart[j][w] = c[j];
    }
    __syncthreads();
    if (tid == 0) {
        unsigned r = 0;
        for (int j = 0; j < 8; j++) {
            unsigned cc = wpart[j][0] + wpart[j][1] + wpart[j][2] + wpart[j][3];
            scnt[j] = cc; sstart[j] = r; r += cc;
        }
        sstart[8] = r;
    }
    __syncthreads();
    if (tid < 8) {
        fstart[b * 8 + tid] = beg + sstart[tid];
        lcur[tid] = beg + sstart[tid];
    }
    if (b == NBC - 1 && tid == 0) fstart[NBF] = end;
    __syncthreads();
    // phase C: scatter via 8 LDS cursors
    for (unsigned i = beg + tid; i < end; i += 256) {
        float v = y1[i];
        int sub = bin_fine(v, lo, invw) & 7;
        unsigned p = atomicAdd(&lcur[sub], 1u);
        y2[p] = v;
    }
    __syncthreads();
    // phase D: fused binsums from freshly-written (L2-hot) y2
    for (int j = w; j < 8; j += 4) {
        unsigned s = beg + sstart[j], e = s + scnt[j];
        double s1 = 0.0, s2 = 0.0;
        for (unsigned i = s + lane; i < e; i += 64) {
            double vd = (double)y2[i];
            s1 += vd; s2 += vd * vd;
        }
        #pragma unroll
        for (int off = 32; off > 0; off >>= 1) {
            s1 += __shfl_xor(s1, off);
            s2 += __shfl_xor(s2, off);
        }
        if (lane == 0) {
            agent_store_f64(&bS1[b * 8 + j], s1);
            agent_store_f64(&bS2[b * 8 + j], s2);
        }
    }
    __threadfence();
    if (tid == 0) {
        unsigned old = atomicAdd(ctr, 1u);
        islast = (old == gridDim.x - 1) ? 1 : 0;
    }
    __syncthreads();
    if (!islast) return;
    __threadfence();
    // last block: exclusive double prefix over all NBF fine bins
    __shared__ double d1[256], d2[256];
    double a1 = 0.0, a2 = 0.0;
    for (int i = 0; i < NBF / 256; i++) {
        int bb = tid * (NBF / 256) + i;
        a1 += agent_load_f64(&bS1[bb]);
        a2 += agent_load_f64(&bS2[bb]);
    }
    d1[tid] = a1; d2[tid] = a2;
    __syncthreads();
    for (int off = 1; off < 256; off <<= 1) {
        double v1 = (tid >= off) ? d1[tid - off] : 0.0;
        double v2 = (tid >= off) ? d2[tid - off] : 0.0;
        __syncthreads();
        d1[tid] += v1; d2[tid] += v2;
        __syncthreads();
    }
    double r1 = d1[tid] - a1, r2 = d2[tid] - a2;
    for (int i = 0; i < NBF / 256; i++) {
        int bb = tid * (NBF / 256) + i;
        P1[bb] = r1; P2[bb] = r2;
        r1 += agent_load_f64(&bS1[bb]);
        r2 += agent_load_f64(&bS2[bb]);
    }
    if (tid == 255) { P1[NBF] = r1; P2[NBF] = r2; }
}

// ============ K4: analytic scorer (block per candidate) + last-block argmin ============
__global__ __launch_bounds__(256) void k_score_final(const float* __restrict__ y2,
                                                     const unsigned* __restrict__ fstart,
                                                     const double* __restrict__ P1,
                                                     const double* __restrict__ P2,
                                                     const float4* __restrict__ params,
                                                     const float2* __restrict__ ranges,
                                                     const float* __restrict__ mm,
                                                     double* score, unsigned* ctr,
                                                     float* __restrict__ out) {
    __shared__ double sC[15], s1v[15], s2v[15];
    __shared__ int islast;
    int tid = threadIdx.x, lane = tid & 63, w = tid >> 6;
    int c = blockIdx.x;
    float lo = mm[2], invw = mm[3];
    float4 p = params[c];
    float s = p.x;
    int zi = (int)(0.0f - p.z);
    double sd = (double)s;

    for (int j = w; j < 15; j += 4) {
        double td = ((double)(j - zi) + 0.5) * sd;
        float tf = (float)td;
        int bf = bin_fine(tf, lo, invw);
        unsigned bb = fstart[bf], be = fstart[bf + 1];
        unsigned cc = 0; double t1 = 0.0, t2 = 0.0;
        for (unsigned i = bb + lane; i < be; i += 64) {
            float v = y2[i];
            if (v < tf) { cc++; double vd = (double)v; t1 += vd; t2 += vd * vd; }
        }
        #pragma unroll
        for (int off = 32; off > 0; off >>= 1) {
            cc += __shfl_xor(cc, off);
            t1 += __shfl_xor(t1, off);
            t2 += __shfl_xor(t2, off);
        }
        if (lane == 0) {
            sC[j]  = (double)bb + (double)cc;
            s1v[j] = P1[bf] + t1;
            s2v[j] = P2[bf] + t2;
        }
    }
    __syncthreads();
    if (tid == 0) {
        double prevC = 0.0, prev1 = 0.0, prev2 = 0.0, sc = 0.0;
        double nTot = (double)fstart[NBF];
        for (int j = 0; j <= 15; j++) {
            double Cc, C1, C2;
            if (j < 15) { Cc = sC[j]; C1 = s1v[j]; C2 = s2v[j]; }
            else        { Cc = nTot; C1 = P1[NBF]; C2 = P2[NBF]; }
            double ms = (double)(j - zi) * sd;
            sc += (Cc - prevC) * ms * ms - 2.0 * ms * (C1 - prev1) + (C2 - prev2);
            prevC = Cc; prev1 = C1; prev2 = C2;
        }
        agent_store_f64(&score[c], sc);
        __threadfence();
        unsigned old = atomicAdd(ctr, 1u);
        islast = (old == gridDim.x - 1) ? 1 : 0;
    }
    __syncthreads();
    if (!islast) return;
    __threadfence();
    // argmin with exact serial tie-break: lexicographic min of (score, index)
    __shared__ double bsc[256];
    __shared__ int bix[256];
    double best = 1.0e300;
    int bidx = 0x7fffffff;
    for (int c2 = tid; c2 < NCAND; c2 += 256) {
        double sc = agent_load_f64(&score[c2]);
        if (sc < best) { best = sc; bidx = c2; }   // ascending c2 keeps first-min
    }
    bsc[tid] = best; bix[tid] = bidx;
    __syncthreads();
    for (int off = 128; off > 0; off >>= 1) {
        if (tid < off) {
            double so = bsc[tid + off]; int io = bix[tid + off];
            if (so < bsc[tid] || (so == bsc[tid] && io < bix[tid])) { bsc[tid] = so; bix[tid] = io; }
        }
        __syncthreads();
    }
    if (tid == 0) {
        float bmin = mm[0], bmax = mm[1];
        if (bix[0] != 0x7fffffff) {
            float2 r = ranges[bix[0]];
            bmin = r.x; bmax = r.y;
        }
        out[0] = bmin; out[1] = bmax;
    }
}

// ============ fallback: round-1 brute force (proven) ============
__global__ __launch_bounds__(256) void k_score_bf(const float* __restrict__ x, int n4,
                                                  const float4* __restrict__ params,
                                                  double* __restrict__ score) {
    const int tid = blockIdx.x * 256 + threadIdx.x;
    const int T = gridDim.x * 256;
    const float4* x4 = (const float4*)x;
    float xs[16];
    #pragma unroll
    for (int k = 0; k < 4; k++) {
        int i4 = tid + k * T;
        float4 v;
        if (i4 < n4) v = x4[i4];
        else { v.x = 0.0f; v.y = 0.0f; v.z = 0.0f; v.w = 0.0f; }
        xs[4*k+0] = v.x; xs[4*k+1] = v.y; xs[4*k+2] = v.z; xs[4*k+3] = v.w;
    }
    int c = (int)((blockIdx.x * 37u) % NCAND);
    for (int k = 0; k < NCAND; k++) {
        float4 p = params[c];
        float s   = rfl_f(p.x);
        float inv = rfl_f(p.y);
        float lo  = rfl_f(p.z);
        float hi  = rfl_f(p.w);
        float acc = 0.0f;
        #pragma unroll
        for (int e = 0; e < 16; e++) {
            float r = rintf(xs[e] * inv);
            r = fminf(fmaxf(r, lo), hi);
            float d = fmaf(r, s, -xs[e]);
            acc = fmaf(d, d, acc);
        }
        #pragma unroll
        for (int off = 32; off > 0; off >>= 1)
            acc += __shfl_xor(acc, off);
        if ((threadIdx.x & 63) == 0)
            atomicAdd(&score[c], (double)acc);
        c++; if (c >= NCAND) c -= NCAND;
    }
}

__global__ void k_final_bf(const double* __restrict__ score,
                           const float2* __restrict__ ranges,
                           const float* __restrict__ mm,
                           float* __restrict__ out) {
    if (blockIdx.x == 0 && threadIdx.x == 0) {
        double best = 1.0e300;
        float bmin = mm[0], bmax = mm[1];
        for (int c = 0; c < NCAND; c++) {
            double sc = score[c];
            if (sc < best) { best = sc; bmin = ranges[c].x; bmax = ranges[c].y; }
        }
        out[0] = bmin;
        out[1] = bmax;
    }
}

extern "C" void kernel_launch(void* const* d_in, const int* in_sizes, int n_in,
                              void* d_out, int out_size, void* d_ws, size_t ws_size,
                              hipStream_t stream) {
    const float* x = (const float*)d_in[0];
    int n  = in_sizes[0];          // 4194304
    int n4 = n / 4;
    float* out = (float*)d_out;

    // ---- workspace layout. Head = zero region (one memset covers it). ----
    char* w = (char*)d_ws;
    unsigned* ctrs     = (unsigned*)w;  w += sizeof(unsigned) * 8;            // [0]=K1 [1]=K2 hist-done [2]=K3 [3]=K4
    unsigned* hist     = (unsigned*)w;  w += sizeof(unsigned) * NBC;
    unsigned* cdelta   = (unsigned*)w;  w += sizeof(unsigned) * NBC;
    double*   score    = (double*)w;    w += sizeof(double) * NCAND;          // zeroed for brute-force path
    size_t zero_bytes  = (size_t)(w - (char*)d_ws);
    float4*   params   = (float4*)w;    w += sizeof(float4) * NCAND;
    float2*   ranges   = (float2*)w;    w += sizeof(float2) * NCAND;
    double*   bS1      = (double*)w;    w += sizeof(double) * NBF;
    double*   bS2      = (double*)w;    w += sizeof(double) * NBF;
    double*   P1       = (double*)w;    w += sizeof(double) * (NBF + 1);
    double*   P2       = (double*)w;    w += sizeof(double) * (NBF + 1);
    unsigned* fstart   = (unsigned*)w;  w += sizeof(unsigned) * (NBF + 1);
    unsigned* binstart = (unsigned*)w;  w += sizeof(unsigned) * (NBC + 1);
    float*    pmin     = (float*)w;     w += sizeof(float) * 1024;
    float*    pmax     = (float*)w;     w += sizeof(float) * 1024;
    float*    mm       = (float*)w;     w += sizeof(float) * 4;
    size_t head = (size_t)(w - (char*)d_ws);
    w = (char*)d_ws + ((head + 15) & ~(size_t)15);
    float*    y1       = (float*)w;     w += sizeof(float) * (size_t)n;
    float*    y2       = (float*)w;     w += sizeof(float) * (size_t)n;
    size_t full_needed  = (size_t)(w - (char*)d_ws);
    size_t brute_needed = head;

    hipMemsetAsync(d_ws, 0, zero_bytes, stream);
    k_minmax_setup<<<1024, 256, 0, stream>>>(x, n4, pmin, pmax, &ctrs[0], params, ranges, mm);

    if (ws_size >= full_needed) {
        k_hist_scatter<<<128, 256, 0, stream>>>(x, n4, mm, hist, cdelta, &ctrs[1], binstart, y1);
        k_subscatter<<<NBC, 256, 0, stream>>>(y1, binstart, mm, y2, fstart, bS1, bS2, &ctrs[2], P1, P2);
        k_score_final<<<NCAND, 256, 0, stream>>>(y2, fstart, P1, P2, params, ranges, mm, score, &ctrs[3], out);
    } else if (ws_size >= brute_needed) {
        int nthreads = (n4 + 3) / 4;
        int blocks = (nthreads + 255) / 256;
        k_score_bf<<<blocks, 256, 0, stream>>>(x, n4, params, score);
        k_final_bf<<<1, 64, 0, stream>>>(score, ranges, mm, out);
    }
}

// Round 5
// 488.438 us; speedup vs baseline: 1.6742x; 1.6742x over previous
//
#include <hip/hip_runtime.h>
#include <math.h>

#define NUM_I 100
#define NZ    16
#define NCAND (NUM_I * NZ)     // 1600
#define NBC   4096             // coarse bins
#define NBF   32768            // fine bins = NBC*8
#define GRID  256
#define BLK   256
#define HPB   (NBC / GRID)     // 16 coarse bins per block
#define FPB   (NBF / GRID)     // 128 fine bins per block
#define F32_EPS 1.1920928955078125e-07f
#define AGENT __HIP_MEMORY_SCOPE_AGENT

// ---------------- workspace layout, shared host/device ----------------
struct WSL {
    unsigned* ctrs;                     // 16 barrier slots (memset to 0)
    float4*   params;  float2* ranges;
    double *bS1, *bS2, *P1, *P2, *pb1, *pb2, *ob1, *ob2, *pbS, *scoreFB;
    int*      pbI;
    unsigned *hist, *cdelta, *binstart, *fstart;
    float *mm, *pmin, *pmax, *y1, *y2;
    size_t zero_bytes, small_needed, full_needed;
};

__host__ __device__ static inline WSL make_ws(char* w0, int n) {
    WSL L; char* w = w0;
    L.ctrs   = (unsigned*)w; w += 64;
    L.params = (float4*)w;   w += sizeof(float4) * NCAND;
    L.ranges = (float2*)w;   w += sizeof(float2) * NCAND;
    L.bS1 = (double*)w; w += sizeof(double) * NBF;
    L.bS2 = (double*)w; w += sizeof(double) * NBF;
    L.P1  = (double*)w; w += sizeof(double) * (NBF + 1);
    L.P2  = (double*)w; w += sizeof(double) * (NBF + 1);
    L.pb1 = (double*)w; w += sizeof(double) * GRID;
    L.pb2 = (double*)w; w += sizeof(double) * GRID;
    L.ob1 = (double*)w; w += sizeof(double) * GRID;
    L.ob2 = (double*)w; w += sizeof(double) * GRID;
    L.pbS = (double*)w; w += sizeof(double) * GRID;
    L.pbI = (int*)w;    w += sizeof(int) * GRID;
    L.hist     = (unsigned*)w; w += sizeof(unsigned) * NBC;
    L.cdelta   = (unsigned*)w; w += sizeof(unsigned) * NBC;
    L.binstart = (unsigned*)w; w += sizeof(unsigned) * (NBC + 1);
    L.fstart   = (unsigned*)w; w += sizeof(unsigned) * (NBF + 1);
    L.mm   = (float*)w; w += sizeof(float) * 4;
    L.pmin = (float*)w; w += sizeof(float) * 1024;
    L.pmax = (float*)w; w += sizeof(float) * 1024;
    size_t head = (size_t)(w - w0);
    head = (head + 15) & ~(size_t)15;
    L.small_needed = head;
    L.y1 = (float*)(w0 + head);
    L.y2 = (float*)(w0 + head + sizeof(float) * (size_t)n);
    L.full_needed = head + 2 * sizeof(float) * (size_t)n;
    L.zero_bytes = 64;
    L.scoreFB = L.bS1;                  // fallback path reuses this region
    return L;
}

// ---------------- device helpers ----------------
static __device__ __forceinline__ float rfl_f(float v) {
    return __int_as_float(__builtin_amdgcn_readfirstlane(__float_as_int(v)));
}
// agent-scope (sc1) store: bypasses non-coherent L2 dirty state -> globally visible on vmcnt ack
static __device__ __forceinline__ void st_sc1_f32(float* p, float v) {
    __hip_atomic_store(p, v, __ATOMIC_RELAXED, AGENT);
}
// global monotone value->fine-bin map; coarse bin == fine>>3 everywhere
static __device__ __forceinline__ int bin_fine(float v, float lo, float invw) {
    int f = (int)floorf((v - lo) * invw);
    return min(max(f, 0), NBF - 1);
}
// global barrier: release on arrival publishes this block's prior plain writes
// (wbl2, once per block); acquire on exit invalidates stale L1/L2 lines.
static __device__ __forceinline__ void gbar(unsigned* ctrs, int k) {
    __syncthreads();
    if (threadIdx.x == 0) {
        __hip_atomic_fetch_add(&ctrs[k], 1u, __ATOMIC_ACQ_REL, AGENT);
        while (__hip_atomic_load(&ctrs[k], __ATOMIC_RELAXED, AGENT) < (unsigned)GRID)
            __builtin_amdgcn_s_sleep(8);
        (void)__hip_atomic_load(&ctrs[k], __ATOMIC_ACQUIRE, AGENT);
    }
    __syncthreads();
}

// ================= the fused kernel =================
__global__ __launch_bounds__(BLK) void k_fused(const float* __restrict__ x, int n, int n4,
                                               char* wsbase, float* __restrict__ out) {
    WSL L = make_ws(wsbase, n);
    __shared__ __align__(16) unsigned char SH[34048];
    const int tid = threadIdx.x, blk = blockIdx.x;
    const int lane = tid & 63, wv = tid >> 6;
    const float4* x4 = (const float4*)x;
    const int per4 = (n4 + GRID - 1) / GRID;
    const int beg4 = blk * per4, end4 = min(beg4 + per4, n4);

    // ---- Ph0: zero hist/cdelta slices + block min/max partials ----
    if (tid < HPB) { L.hist[blk * HPB + tid] = 0u; L.cdelta[blk * HPB + tid] = 0u; }
    {
        float* rmin = (float*)SH; float* rmax = rmin + BLK;
        float lmin = 3.0e38f, lmax = -3.0e38f;
        for (int i = beg4 + tid; i < end4; i += BLK) {
            float4 v = x4[i];
            lmin = fminf(lmin, fminf(fminf(v.x, v.y), fminf(v.z, v.w)));
            lmax = fmaxf(lmax, fmaxf(fmaxf(v.x, v.y), fmaxf(v.z, v.w)));
        }
        rmin[tid] = lmin; rmax[tid] = lmax;
        __syncthreads();
        for (int s = 128; s > 0; s >>= 1) {
            if (tid < s) {
                rmin[tid] = fminf(rmin[tid], rmin[tid + s]);
                rmax[tid] = fmaxf(rmax[tid], rmax[tid + s]);
            }
            __syncthreads();
        }
        if (tid == 0) { L.pmin[blk] = rmin[0]; L.pmax[blk] = rmax[0]; }
    }
    gbar(L.ctrs, 0);

    // ---- Ph1 (block 0): final min/max + candidate params ----
    if (blk == 0) {
        float* rmin = (float*)SH; float* rmax = rmin + BLK;
        float lmin = (tid < GRID) ? L.pmin[tid] : 3.0e38f;
        float lmax = (tid < GRID) ? L.pmax[tid] : -3.0e38f;
        rmin[tid] = lmin; rmax[tid] = lmax;
        __syncthreads();
        for (int s = 128; s > 0; s >>= 1) {
            if (tid < s) {
                rmin[tid] = fminf(rmin[tid], rmin[tid + s]);
                rmax[tid] = fmaxf(rmax[tid], rmax[tid + s]);
            }
            __syncthreads();
        }
        float x_min = rmin[0], x_max = rmax[0];
        {
#pragma clang fp contract(off)
            if (tid == 0) {
                L.mm[0] = x_min; L.mm[1] = x_max;
                float range = x_max - x_min;
                L.mm[2] = x_min;
                L.mm[3] = (range > 0.0f) ? ((float)NBF / range) : 0.0f;
            }
            float xrange = x_max - x_min;
            float step = xrange / 100.0f;
            for (int c = tid; c < NCAND; c += BLK) {
                int ii = c >> 4;
                int z  = c & 15;
                float fi = (float)(ii + 1);
                float tmp_max   = step * fi;
                float tmp_delta = tmp_max / 15.0f;
                float t = (float)z * tmp_delta;
                float new_min = fmaxf(-t, x_min);
                float new_max = fminf(tmp_max - t, x_max);
                float min_neg = fminf(new_min, 0.0f);
                float max_pos = fmaxf(new_max, 0.0f);
                float scale = fmaxf((max_pos - min_neg) / 15.0f, F32_EPS);
                float zp = 0.0f - rintf(min_neg / scale);
                zp = fminf(fmaxf(zp, 0.0f), 15.0f);
                float inv = (float)(1.0 / (double)scale);
                L.params[c] = make_float4(scale, inv, 0.0f - zp, 15.0f - zp);
                L.ranges[c] = make_float2(new_min, new_max);
            }
        }
    }
    gbar(L.ctrs, 1);

    const float lo = L.mm[2], invw = L.mm[3];

    // ---- Ph2: coarse histogram (LDS-private, kept for Ph3) ----
    unsigned* lhist = (unsigned*)SH;                 // 16 KB
    for (int k = tid; k < NBC; k += BLK) lhist[k] = 0u;
    __syncthreads();
    for (int i = beg4 + tid; i < end4; i += BLK) {
        float4 v = x4[i];
        atomicAdd(&lhist[bin_fine(v.x, lo, invw) >> 3], 1u);
        atomicAdd(&lhist[bin_fine(v.y, lo, invw) >> 3], 1u);
        atomicAdd(&lhist[bin_fine(v.z, lo, invw) >> 3], 1u);
        atomicAdd(&lhist[bin_fine(v.w, lo, invw) >> 3], 1u);
    }
    __syncthreads();
    for (int k = tid; k < NBC; k += BLK) {
        unsigned c = lhist[k];
        if (c) atomicAdd(&L.hist[k], c);
    }
    gbar(L.ctrs, 2);

    // ---- Ph3: redundant global scan + per-block reservation + scatter -> y1 ----
    {
        unsigned* lstart = (unsigned*)(SH + 16384);  // 16 KB
        unsigned* lscan  = (unsigned*)(SH + 32768);  // 1 KB
        unsigned gh[HPB]; unsigned psum = 0;
        #pragma unroll
        for (int k = 0; k < HPB; k++) { gh[k] = L.hist[tid * HPB + k]; psum += gh[k]; }
        lscan[tid] = psum;
        __syncthreads();
        for (int off = 1; off < BLK; off <<= 1) {
            unsigned v = (tid >= off) ? lscan[tid - off] : 0u;
            __syncthreads();
            lscan[tid] += v;
            __syncthreads();
        }
        unsigned run = lscan[tid] - psum;            // exclusive
        #pragma unroll
        for (int k = 0; k < HPB; k++) { lstart[tid * HPB + k] = run; run += gh[k]; }
        if (blk == 0) {
            for (int k = 0; k < HPB; k++) L.binstart[tid * HPB + k] = lstart[tid * HPB + k];
            if (tid == BLK - 1) L.binstart[NBC] = run;
        }
        __syncthreads();
        for (int k = 0; k < HPB; k++) {
            int bb = tid * HPB + k;
            unsigned c = lhist[bb];
            if (c) { unsigned d = atomicAdd(&L.cdelta[bb], c); lstart[bb] += d; }
        }
        __syncthreads();
        for (int i = beg4 + tid; i < end4; i += BLK) {
            float4 v = x4[i];
            unsigned p0 = atomicAdd(&lstart[bin_fine(v.x, lo, invw) >> 3], 1u); st_sc1_f32(&L.y1[p0], v.x);
            unsigned p1 = atomicAdd(&lstart[bin_fine(v.y, lo, invw) >> 3], 1u); st_sc1_f32(&L.y1[p1], v.y);
            unsigned p2 = atomicAdd(&lstart[bin_fine(v.z, lo, invw) >> 3], 1u); st_sc1_f32(&L.y1[p2], v.z);
            unsigned p3 = atomicAdd(&lstart[bin_fine(v.w, lo, invw) >> 3], 1u); st_sc1_f32(&L.y1[p3], v.w);
        }
    }
    gbar(L.ctrs, 3);

    // ---- Ph4: sub-scatter into 8 fine bins + fused binsums (stride-assigned bins) ----
    {
        unsigned* scnt   = (unsigned*)SH;            // 8
        unsigned* sstart = scnt + 8;                 // 9
        unsigned* lcur   = sstart + 9;               // 8
        unsigned* wpart  = lcur + 8;                 // 32
        for (int k = 0; k < HPB; k++) {
            int b = blk + GRID * k;                  // stride -> load balance across blocks
            unsigned beg = L.binstart[b], end = L.binstart[b + 1];
            unsigned c8[8] = {0,0,0,0,0,0,0,0};
            for (unsigned i = beg + tid; i < end; i += BLK) {
                int sub = bin_fine(L.y1[i], lo, invw) & 7;
                #pragma unroll
                for (int j = 0; j < 8; j++) c8[j] += (sub == j) ? 1u : 0u;
            }
            #pragma unroll
            for (int j = 0; j < 8; j++) {
                #pragma unroll
                for (int off = 32; off > 0; off >>= 1) c8[j] += __shfl_xor(c8[j], off);
            }
            if (lane == 0) {
                #pragma unroll
                for (int j = 0; j < 8; j++) wpart[j * 4 + wv] = c8[j];
            }
            __syncthreads();
            if (tid == 0) {
                unsigned r = 0;
                for (int j = 0; j < 8; j++) {
                    unsigned cc = wpart[j*4] + wpart[j*4+1] + wpart[j*4+2] + wpart[j*4+3];
                    scnt[j] = cc; sstart[j] = r; r += cc;
                }
                sstart[8] = r;
            }
            __syncthreads();
            if (tid < 8) { L.fstart[b * 8 + tid] = beg + sstart[tid]; lcur[tid] = beg + sstart[tid]; }
            __syncthreads();
            for (unsigned i = beg + tid; i < end; i += BLK) {
                float v = L.y1[i];
                int sub = bin_fine(v, lo, invw) & 7;
                unsigned p = atomicAdd(&lcur[sub], 1u);
                st_sc1_f32(&L.y2[p], v);
            }
            __syncthreads();
            for (int j = wv; j < 8; j += 4) {
                unsigned s0 = beg + sstart[j], e0 = s0 + scnt[j];
                double s1 = 0.0, s2 = 0.0;
                for (unsigned i = s0 + lane; i < e0; i += 64) {
                    double vd = (double)L.y2[i];
                    s1 += vd; s2 += vd * vd;
                }
                #pragma unroll
                for (int off = 32; off > 0; off >>= 1) {
                    s1 += __shfl_xor(s1, off);
                    s2 += __shfl_xor(s2, off);
                }
                if (lane == 0) { L.bS1[b * 8 + j] = s1; L.bS2[b * 8 + j] = s2; }
            }
            __syncthreads();
        }
    }
    gbar(L.ctrs, 4);

    // ---- Ph5: per-block partial totals over its 128-fine-bin range ----
    {
        double* d1 = (double*)SH; double* d2 = d1 + BLK;
        int base = blk * FPB;
        double a1 = 0.0, a2 = 0.0;
        if (tid < FPB) { a1 = L.bS1[base + tid]; a2 = L.bS2[base + tid]; }
        d1[tid] = a1; d2[tid] = a2;
        __syncthreads();
        for (int s = 128; s > 0; s >>= 1) {
            if (tid < s) { d1[tid] += d1[tid + s]; d2[tid] += d2[tid + s]; }
            __syncthreads();
        }
        if (tid == 0) { L.pb1[blk] = d1[0]; L.pb2[blk] = d2[0]; }
    }
    gbar(L.ctrs, 5);

    // ---- Ph6 (block 0): exclusive scan over 256 block partials ----
    if (blk == 0 && tid == 0) {
        double r1 = 0.0, r2 = 0.0;
        for (int i = 0; i < GRID; i++) { L.ob1[i] = r1; L.ob2[i] = r2; r1 += L.pb1[i]; r2 += L.pb2[i]; }
        L.P1[NBF] = r1; L.P2[NBF] = r2;
        L.fstart[NBF] = (unsigned)n;
    }
    gbar(L.ctrs, 6);

    // ---- Ph7: per-block exclusive prefix over its 128 fine bins ----
    {
        double* a1s = (double*)SH; double* a2s = a1s + FPB;
        int base = blk * FPB;
        double own1 = 0.0, own2 = 0.0;
        if (tid < FPB) {
            own1 = L.bS1[base + tid]; own2 = L.bS2[base + tid];
            a1s[tid] = own1; a2s[tid] = own2;
        }
        __syncthreads();
        for (int off = 1; off < FPB; off <<= 1) {
            double v1 = 0.0, v2 = 0.0;
            if (tid < FPB && tid >= off) { v1 = a1s[tid - off]; v2 = a2s[tid - off]; }
            __syncthreads();
            if (tid < FPB) { a1s[tid] += v1; a2s[tid] += v2; }
            __syncthreads();
        }
        if (tid < FPB) {
            L.P1[base + tid] = L.ob1[blk] + a1s[tid] - own1;
            L.P2[base + tid] = L.ob2[blk] + a2s[tid] - own2;
        }
    }
    gbar(L.ctrs, 7);

    // ---- Ph8: analytic scorer, candidates stride-assigned; per-block argmin ----
    {
        double* sC  = (double*)SH;
        double* s1v = sC + 16;
        double* s2v = s1v + 16;
        double bestS = 1.0e300; int bestI = 0x7fffffff;
        for (int cand = blk; cand < NCAND; cand += GRID) {
            float4 p = L.params[cand];
            int zi = (int)(0.0f - p.z);
            double sd = (double)p.x;
            __syncthreads();                          // protect sC reuse
            for (int j = wv; j < 15; j += 4) {
                double td = ((double)(j - zi) + 0.5) * sd;
                float tf = (float)td;
                int bf = bin_fine(tf, lo, invw);
                unsigned bb = L.fstart[bf], be = L.fstart[bf + 1];
                unsigned cc = 0; double t1 = 0.0, t2 = 0.0;
                for (unsigned i = bb + lane; i < be; i += 64) {
                    float v = L.y2[i];
                    if (v < tf) { cc++; double vd = (double)v; t1 += vd; t2 += vd * vd; }
                }
                #pragma unroll
                for (int off = 32; off > 0; off >>= 1) {
                    cc += __shfl_xor(cc, off);
                    t1 += __shfl_xor(t1, off);
                    t2 += __shfl_xor(t2, off);
                }
                if (lane == 0) {
                    sC[j]  = (double)bb + (double)cc;
                    s1v[j] = L.P1[bf] + t1;
                    s2v[j] = L.P2[bf] + t2;
                }
            }
            __syncthreads();
            if (tid == 0) {
                double prevC = 0.0, prev1 = 0.0, prev2 = 0.0, sc = 0.0;
                double nTot = (double)L.fstart[NBF];
                for (int j = 0; j <= 15; j++) {
                    double Cc, C1, C2;
                    if (j < 15) { Cc = sC[j]; C1 = s1v[j]; C2 = s2v[j]; }
                    else        { Cc = nTot; C1 = L.P1[NBF]; C2 = L.P2[NBF]; }
                    double ms = (double)(j - zi) * sd;
                    sc += (Cc - prevC) * ms * ms - 2.0 * ms * (C1 - prev1) + (C2 - prev2);
                    prevC = Cc; prev1 = C1; prev2 = C2;
                }
                if (sc < bestS) { bestS = sc; bestI = cand; }  // ascending cand keeps first-min
            }
        }
        if (tid == 0) { L.pbS[blk] = bestS; L.pbI[blk] = bestI; }
    }
    gbar(L.ctrs, 8);

    // ---- Ph9 (block 0): lexicographic argmin over block partials ----
    if (blk == 0) {
        double* bsc = (double*)SH;
        int*    bix = (int*)(SH + sizeof(double) * BLK);
        double bv = (tid < GRID) ? L.pbS[tid] : 1.0e300;
        int    bi = (tid < GRID) ? L.pbI[tid] : 0x7fffffff;
        bsc[tid] = bv; bix[tid] = bi;
        __syncthreads();
        for (int s = 128; s > 0; s >>= 1) {
            if (tid < s) {
                double so = bsc[tid + s]; int io = bix[tid + s];
                if (so < bsc[tid] || (so == bsc[tid] && io < bix[tid])) { bsc[tid] = so; bix[tid] = io; }
            }
            __syncthreads();
        }
        if (tid == 0) {
            float bmin = L.mm[0], bmax = L.mm[1];
            if (bix[0] != 0x7fffffff) {
                float2 r = L.ranges[bix[0]];
                bmin = r.x; bmax = r.y;
            }
            out[0] = bmin; out[1] = bmax;
        }
    }
}

// ================= fallback path (round-1/3 proven, stream-ordered) =================
__global__ __launch_bounds__(256) void k_minmax_fb(const float* __restrict__ x, int n4,
                                                   float* __restrict__ pmin,
                                                   float* __restrict__ pmax) {
    int tid = blockIdx.x * blockDim.x + threadIdx.x;
    int stride = gridDim.x * blockDim.x;
    const float4* x4 = (const float4*)x;
    float lmin = 3.0e38f, lmax = -3.0e38f;
    for (int i = tid; i < n4; i += stride) {
        float4 v = x4[i];
        lmin = fminf(lmin, fminf(fminf(v.x, v.y), fminf(v.z, v.w)));
        lmax = fmaxf(lmax, fmaxf(fmaxf(v.x, v.y), fmaxf(v.z, v.w)));
    }
    #pragma unroll
    for (int off = 32; off > 0; off >>= 1) {
        lmin = fminf(lmin, __shfl_xor(lmin, off));
        lmax = fmaxf(lmax, __shfl_xor(lmax, off));
    }
    __shared__ float smin[4], smax[4];
    int w = threadIdx.x >> 6;
    if ((threadIdx.x & 63) == 0) { smin[w] = lmin; smax[w] = lmax; }
    __syncthreads();
    if (threadIdx.x == 0) {
        pmin[blockIdx.x] = fminf(fminf(smin[0], smin[1]), fminf(smin[2], smin[3]));
        pmax[blockIdx.x] = fmaxf(fmaxf(smax[0], smax[1]), fmaxf(smax[2], smax[3]));
    }
}

__global__ __launch_bounds__(256) void k_params_fb(const float* __restrict__ pmin,
                                                   const float* __restrict__ pmax, int nb,
                                                   float4* __restrict__ params,
                                                   float2* __restrict__ ranges,
                                                   double* __restrict__ score,
                                                   float* __restrict__ mm) {
#pragma clang fp contract(off)
    __shared__ float smin[256], smax[256];
    float lmin = 3.0e38f, lmax = -3.0e38f;
    for (int i = threadIdx.x; i < nb; i += 256) {
        lmin = fminf(lmin, pmin[i]);
        lmax = fmaxf(lmax, pmax[i]);
    }
    smin[threadIdx.x] = lmin; smax[threadIdx.x] = lmax;
    __syncthreads();
    for (int s = 128; s > 0; s >>= 1) {
        if (threadIdx.x < s) {
            smin[threadIdx.x] = fminf(smin[threadIdx.x], smin[threadIdx.x + s]);
            smax[threadIdx.x] = fmaxf(smax[threadIdx.x], smax[threadIdx.x + s]);
        }
        __syncthreads();
    }
    float x_min = smin[0], x_max = smax[0];
    if (threadIdx.x == 0) { mm[0] = x_min; mm[1] = x_max; }
    float xrange = x_max - x_min;
    float step = xrange / 100.0f;
    for (int c = threadIdx.x; c < NCAND; c += 256) {
        int ii = c >> 4;
        int z  = c & 15;
        float fi = (float)(ii + 1);
        float tmp_max   = step * fi;
        float tmp_delta = tmp_max / 15.0f;
        float t = (float)z * tmp_delta;
        float new_min = fmaxf(-t, x_min);
        float new_max = fminf(tmp_max - t, x_max);
        float min_neg = fminf(new_min, 0.0f);
        float max_pos = fmaxf(new_max, 0.0f);
        float scale = fmaxf((max_pos - min_neg) / 15.0f, F32_EPS);
        float zp = 0.0f - rintf(min_neg / scale);
        zp = fminf(fmaxf(zp, 0.0f), 15.0f);
        float inv = (float)(1.0 / (double)scale);
        params[c] = make_float4(scale, inv, 0.0f - zp, 15.0f - zp);
        ranges[c] = make_float2(new_min, new_max);
        score[c]  = 0.0;
    }
}

__global__ __launch_bounds__(256) void k_score_bf(const float* __restrict__ x, int n4,
                                                  const float4* __restrict__ params,
                                                  double* __restrict__ score) {
    const int tid = blockIdx.x * 256 + threadIdx.x;
    const int T = gridDim.x * 256;
    const float4* x4 = (const float4*)x;
    float xs[16];
    #pragma unroll
    for (int k = 0; k < 4; k++) {
        int i4 = tid + k * T;
        float4 v;
        if (i4 < n4) v = x4[i4];
        else { v.x = 0.0f; v.y = 0.0f; v.z = 0.0f; v.w = 0.0f; }
        xs[4*k+0] = v.x; xs[4*k+1] = v.y; xs[4*k+2] = v.z; xs[4*k+3] = v.w;
    }
    int c = (int)((blockIdx.x * 37u) % NCAND);
    for (int k = 0; k < NCAND; k++) {
        float4 p = params[c];
        float s   = rfl_f(p.x);
        float inv = rfl_f(p.y);
        float lo  = rfl_f(p.z);
        float hi  = rfl_f(p.w);
        float acc = 0.0f;
        #pragma unroll
        for (int e = 0; e < 16; e++) {
            float r = rintf(xs[e] * inv);
            r = fminf(fmaxf(r, lo), hi);
            float d = fmaf(r, s, -xs[e]);
            acc = fmaf(d, d, acc);
        }
        #pragma unroll
        for (int off = 32; off > 0; off >>= 1)
            acc += __shfl_xor(acc, off);
        if ((threadIdx.x & 63) == 0)
            atomicAdd(&score[c], (double)acc);
        c++; if (c >= NCAND) c -= NCAND;
    }
}

__global__ void k_final_fb(const double* __restrict__ score,
                           const float2* __restrict__ ranges,
                           const float* __restrict__ mm,
                           float* __restrict__ out) {
    if (blockIdx.x == 0 && threadIdx.x == 0) {
        double best = 1.0e300;
        float bmin = mm[0], bmax = mm[1];
        for (int c = 0; c < NCAND; c++) {
            double sc = score[c];
            if (sc < best) { best = sc; bmin = ranges[c].x; bmax = ranges[c].y; }
        }
        out[0] = bmin;
        out[1] = bmax;
    }
}

extern "C" void kernel_launch(void* const* d_in, const int* in_sizes, int n_in,
                              void* d_out, int out_size, void* d_ws, size_t ws_size,
                              hipStream_t stream) {
    const float* x = (const float*)d_in[0];
    int n  = in_sizes[0];          // 4194304
    int n4 = n / 4;
    float* out = (float*)d_out;
    WSL L = make_ws((char*)d_ws, n);

    if (ws_size >= L.full_needed && (n % 4) == 0) {
        hipMemsetAsync(d_ws, 0, L.zero_bytes, stream);     // barrier counters only
        k_fused<<<GRID, BLK, 0, stream>>>(x, n, n4, (char*)d_ws, out);
    } else if (ws_size >= L.small_needed) {
        k_minmax_fb<<<1024, 256, 0, stream>>>(x, n4, L.pmin, L.pmax);
        k_params_fb<<<1, 256, 0, stream>>>(L.pmin, L.pmax, 1024, L.params, L.ranges, L.scoreFB, L.mm);
        int blocks = ((n4 + 3) / 4 + 255) / 256;
        k_score_bf<<<blocks, 256, 0, stream>>>(x, n4, L.params, L.scoreFB);
        k_final_fb<<<1, 64, 0, stream>>>(L.scoreFB, L.ranges, L.mm, out);
    }
}

// Round 6
// 447.840 us; speedup vs baseline: 1.8260x; 1.0907x over previous
//
#include <hip/hip_runtime.h>
#include <math.h>

#define NUM_I 100
#define NZ    16
#define NCAND (NUM_I * NZ)     // 1600
#define NBC   4096             // coarse bins
#define NBF   32768            // fine bins = NBC*8
#define GRID  256
#define BLK   256
#define HPB   (NBC / GRID)     // 16 coarse bins per thread-slice / per K1 block
#define FPB   (NBF / GRID)     // 128 fine bins per block (chunk)
#define F32_EPS 1.1920928955078125e-07f
#define AGENT __HIP_MEMORY_SCOPE_AGENT

// ---------------- workspace layout, shared host/device ----------------
struct WSL {
    unsigned* ctrs;                     // 16 barrier slots (memset to 0)
    float4*   params;  float2* ranges;
    double *bS1, *bS2, *P1, *P2, *chS1, *chS2, *pbS, *scoreFB;
    int*      pbI;
    unsigned *hist, *cdelta, *fstart;
    float *mm, *pmin, *pmax, *y1, *y2;
    size_t small_needed, full_needed;
};

__host__ __device__ static inline WSL make_ws(char* w0, int n) {
    WSL L; char* w = w0;
    L.ctrs   = (unsigned*)w; w += 64;
    L.params = (float4*)w;   w += sizeof(float4) * NCAND;
    L.ranges = (float2*)w;   w += sizeof(float2) * NCAND;
    L.bS1  = (double*)w; w += sizeof(double) * NBF;
    L.bS2  = (double*)w; w += sizeof(double) * NBF;
    L.P1   = (double*)w; w += sizeof(double) * (NBF + 1);
    L.P2   = (double*)w; w += sizeof(double) * (NBF + 1);
    L.chS1 = (double*)w; w += sizeof(double) * GRID;
    L.chS2 = (double*)w; w += sizeof(double) * GRID;
    L.pbS  = (double*)w; w += sizeof(double) * GRID;
    L.pbI  = (int*)w;    w += sizeof(int) * GRID;
    L.hist   = (unsigned*)w; w += sizeof(unsigned) * NBC;
    L.cdelta = (unsigned*)w; w += sizeof(unsigned) * NBC;
    L.fstart = (unsigned*)w; w += sizeof(unsigned) * (NBF + 1);
    L.mm   = (float*)w; w += sizeof(float) * 4;
    L.pmin = (float*)w; w += sizeof(float) * GRID;
    L.pmax = (float*)w; w += sizeof(float) * GRID;
    size_t head = (size_t)(w - w0);
    head = (head + 15) & ~(size_t)15;
    L.small_needed = head;
    L.y1 = (float*)(w0 + head);
    L.y2 = (float*)(w0 + head + sizeof(float) * (size_t)n);
    L.full_needed = head + 2 * sizeof(float) * (size_t)n;
    L.scoreFB = L.bS1;                  // fallback path reuses this region
    return L;
}

// ---------------- device helpers ----------------
static __device__ __forceinline__ float rfl_f(float v) {
    return __int_as_float(__builtin_amdgcn_readfirstlane(__float_as_int(v)));
}
static __device__ __forceinline__ float agent_load_f32(const float* p) {
    return __hip_atomic_load(p, __ATOMIC_RELAXED, AGENT);
}
static __device__ __forceinline__ void agent_store_f32(float* p, float v) {
    __hip_atomic_store(p, v, __ATOMIC_RELAXED, AGENT);
}
// global monotone value->fine-bin map; coarse bin == fine>>3 everywhere
static __device__ __forceinline__ int bin_fine(float v, float lo, float invw) {
    int f = (int)floorf((v - lo) * invw);
    return min(max(f, 0), NBF - 1);
}
// global barrier, tid0-only cache maintenance:
// ACQ_REL RMW on arrival = release (wbl2: publish this block's cached writes),
// ACQUIRE load on exit = invalidate (see other blocks' published writes).
static __device__ __forceinline__ void gbar(unsigned* ctr) {
    __syncthreads();
    if (threadIdx.x == 0) {
        __hip_atomic_fetch_add(ctr, 1u, __ATOMIC_ACQ_REL, AGENT);
        while (__hip_atomic_load(ctr, __ATOMIC_RELAXED, AGENT) < (unsigned)GRID)
            __builtin_amdgcn_s_sleep(8);
        (void)__hip_atomic_load(ctr, __ATOMIC_ACQUIRE, AGENT);
    }
    __syncthreads();
}

// ============ K1: min/max partials + last-block(final+params) + zero slices ============
__global__ __launch_bounds__(BLK) void k_minmax_setup(const float* __restrict__ x, int n4,
                                                      char* wsbase, int n) {
#pragma clang fp contract(off)
    WSL L = make_ws(wsbase, n);
    __shared__ float rmin[BLK], rmax[BLK];
    __shared__ int islast;
    int tid = threadIdx.x, blk = blockIdx.x;
    // zero the global arrays K_main's atomics need (kernel boundary publishes)
    if (tid < HPB) { L.hist[blk * HPB + tid] = 0u; L.cdelta[blk * HPB + tid] = 0u; }
    if (tid == 0)  { L.chS1[blk] = 0.0; L.chS2[blk] = 0.0; }

    int gtid = blk * BLK + tid;
    int stride = gridDim.x * BLK;
    const float4* x4 = (const float4*)x;
    float lmin = 3.0e38f, lmax = -3.0e38f;
    for (int i = gtid; i < n4; i += stride) {
        float4 v = x4[i];
        lmin = fminf(lmin, fminf(fminf(v.x, v.y), fminf(v.z, v.w)));
        lmax = fmaxf(lmax, fmaxf(fmaxf(v.x, v.y), fmaxf(v.z, v.w)));
    }
    rmin[tid] = lmin; rmax[tid] = lmax;
    __syncthreads();
    for (int s = 128; s > 0; s >>= 1) {
        if (tid < s) {
            rmin[tid] = fminf(rmin[tid], rmin[tid + s]);
            rmax[tid] = fmaxf(rmax[tid], rmax[tid + s]);
        }
        __syncthreads();
    }
    if (tid == 0) {
        agent_store_f32(&L.pmin[blk], rmin[0]);
        agent_store_f32(&L.pmax[blk], rmax[0]);
        __threadfence();
        unsigned old = atomicAdd(&L.ctrs[15], 1u);
        islast = (old == gridDim.x - 1) ? 1 : 0;
    }
    __syncthreads();
    if (!islast) return;
    __threadfence();

    lmin = 3.0e38f; lmax = -3.0e38f;
    for (int i = tid; i < (int)gridDim.x; i += BLK) {
        lmin = fminf(lmin, agent_load_f32(&L.pmin[i]));
        lmax = fmaxf(lmax, agent_load_f32(&L.pmax[i]));
    }
    rmin[tid] = lmin; rmax[tid] = lmax;
    __syncthreads();
    for (int s = 128; s > 0; s >>= 1) {
        if (tid < s) {
            rmin[tid] = fminf(rmin[tid], rmin[tid + s]);
            rmax[tid] = fmaxf(rmax[tid], rmax[tid + s]);
        }
        __syncthreads();
    }
    float x_min = rmin[0], x_max = rmax[0];
    if (tid == 0) {
        L.mm[0] = x_min; L.mm[1] = x_max;
        float range = x_max - x_min;
        L.mm[2] = x_min;
        L.mm[3] = (range > 0.0f) ? ((float)NBF / range) : 0.0f;
    }
    float xrange = x_max - x_min;
    float step = xrange / 100.0f;
    for (int c = tid; c < NCAND; c += BLK) {
        int ii = c >> 4;
        int z  = c & 15;
        float fi = (float)(ii + 1);
        float tmp_max   = step * fi;
        float tmp_delta = tmp_max / 15.0f;
        float t = (float)z * tmp_delta;
        float new_min = fmaxf(-t, x_min);
        float new_max = fminf(tmp_max - t, x_max);
        float min_neg = fminf(new_min, 0.0f);
        float max_pos = fmaxf(new_max, 0.0f);
        float scale = fmaxf((max_pos - min_neg) / 15.0f, F32_EPS);
        float zp = 0.0f - rintf(min_neg / scale);
        zp = fminf(fmaxf(zp, 0.0f), 15.0f);
        float inv = (float)(1.0 / (double)scale);
        L.params[c] = make_float4(scale, inv, 0.0f - zp, 15.0f - zp);
        L.ranges[c] = make_float2(new_min, new_max);
    }
}

// ============ K2: hist -> scatter -> subscatter+sums -> prefix -> score -> argmin ============
__global__ __launch_bounds__(BLK) void k_main(const float* __restrict__ x, int n, int n4,
                                              char* wsbase, float* __restrict__ out) {
    WSL L = make_ws(wsbase, n);
    __shared__ __align__(16) unsigned gstart[NBC + 1];        // 16388 B, persists Ph3->Ph4
    __shared__ __align__(16) unsigned char SHB[16384];        // lhist / doubles, phase-reused
    __shared__ __align__(16) unsigned char SHC[2064];         // scan buf / small arrays
    const int tid = threadIdx.x, blk = blockIdx.x;
    const int lane = tid & 63, wv = tid >> 6;
    const float4* x4 = (const float4*)x;
    const int per4 = (n4 + GRID - 1) / GRID;
    const int beg4 = blk * per4, end4 = min(beg4 + per4, n4);
    const float lo = L.mm[2], invw = L.mm[3];

    // ---- Ph2: coarse histogram (LDS-private; lhist kept for Ph3 reservation) ----
    unsigned* lhist = (unsigned*)SHB;
    for (int k = tid; k < NBC; k += BLK) lhist[k] = 0u;
    __syncthreads();
    for (int i = beg4 + tid; i < end4; i += BLK) {
        float4 v = x4[i];
        atomicAdd(&lhist[bin_fine(v.x, lo, invw) >> 3], 1u);
        atomicAdd(&lhist[bin_fine(v.y, lo, invw) >> 3], 1u);
        atomicAdd(&lhist[bin_fine(v.z, lo, invw) >> 3], 1u);
        atomicAdd(&lhist[bin_fine(v.w, lo, invw) >> 3], 1u);
    }
    __syncthreads();
    for (int k = tid; k < NBC; k += BLK) {
        unsigned c = lhist[k];
        if (c) atomicAdd(&L.hist[k], c);
    }
    gbar(&L.ctrs[0]);

    // ---- Ph3: redundant global scan -> gstart; reserve; scatter -> y1 (plain stores) ----
    {
        unsigned* lscan = (unsigned*)SHC;
        unsigned gh[HPB]; unsigned psum = 0;
        #pragma unroll
        for (int k = 0; k < HPB; k++) { gh[k] = L.hist[tid * HPB + k]; psum += gh[k]; }
        lscan[tid] = psum;
        __syncthreads();
        for (int off = 1; off < BLK; off <<= 1) {
            unsigned v = (tid >= off) ? lscan[tid - off] : 0u;
            __syncthreads();
            lscan[tid] += v;
            __syncthreads();
        }
        unsigned run = lscan[tid] - psum;            // exclusive
        #pragma unroll
        for (int k = 0; k < HPB; k++) { gstart[tid * HPB + k] = run; run += gh[k]; }
        if (tid == BLK - 1) gstart[NBC] = run;       // == n
        __syncthreads();
        // reserve per-block region per bin; lhist becomes the cursor in-place
        for (int k = 0; k < HPB; k++) {
            int bb = tid * HPB + k;
            unsigned c = lhist[bb];
            unsigned cur = gstart[bb];
            if (c) cur += atomicAdd(&L.cdelta[bb], c);
            lhist[bb] = cur;
        }
        __syncthreads();
        for (int i = beg4 + tid; i < end4; i += BLK) {
            float4 v = x4[i];
            unsigned p0 = atomicAdd(&lhist[bin_fine(v.x, lo, invw) >> 3], 1u); L.y1[p0] = v.x;
            unsigned p1 = atomicAdd(&lhist[bin_fine(v.y, lo, invw) >> 3], 1u); L.y1[p1] = v.y;
            unsigned p2 = atomicAdd(&lhist[bin_fine(v.z, lo, invw) >> 3], 1u); L.y1[p2] = v.z;
            unsigned p3 = atomicAdd(&lhist[bin_fine(v.w, lo, invw) >> 3], 1u); L.y1[p3] = v.w;
        }
    }
    gbar(&L.ctrs[1]);   // publishes y1

    // ---- Ph4: sub-scatter (stride-assigned coarse bins) + binsums + chunk atomics ----
    {
        unsigned* scnt   = (unsigned*)SHC;           // 8
        unsigned* sstart = scnt + 8;                 // 9
        unsigned* lcur   = sstart + 9;               // 8
        unsigned* wpart  = lcur + 8;                 // 32
        for (int k = 0; k < HPB; k++) {
            int b = blk + GRID * k;                  // stride -> load balance
            unsigned beg = gstart[b], end = gstart[b + 1];
            unsigned c8[8] = {0,0,0,0,0,0,0,0};
            for (unsigned i = beg + tid; i < end; i += BLK) {
                int sub = bin_fine(L.y1[i], lo, invw) & 7;
                #pragma unroll
                for (int j = 0; j < 8; j++) c8[j] += (sub == j) ? 1u : 0u;
            }
            #pragma unroll
            for (int j = 0; j < 8; j++) {
                #pragma unroll
                for (int off = 32; off > 0; off >>= 1) c8[j] += __shfl_xor(c8[j], off);
            }
            if (lane == 0) {
                #pragma unroll
                for (int j = 0; j < 8; j++) wpart[j * 4 + wv] = c8[j];
            }
            __syncthreads();
            if (tid == 0) {
                unsigned r = 0;
                for (int j = 0; j < 8; j++) {
                    unsigned cc = wpart[j*4] + wpart[j*4+1] + wpart[j*4+2] + wpart[j*4+3];
                    scnt[j] = cc; sstart[j] = r; r += cc;
                }
                sstart[8] = r;
            }
            __syncthreads();
            if (tid < 8) { L.fstart[b * 8 + tid] = beg + sstart[tid]; lcur[tid] = beg + sstart[tid]; }
            __syncthreads();
            for (unsigned i = beg + tid; i < end; i += BLK) {
                float v = L.y1[i];
                int sub = bin_fine(v, lo, invw) & 7;
                unsigned p = atomicAdd(&lcur[sub], 1u);
                L.y2[p] = v;                          // plain cached store
            }
            __syncthreads();
            for (int j = wv; j < 8; j += 4) {
                unsigned s0 = beg + sstart[j], e0 = s0 + scnt[j];
                double s1 = 0.0, s2 = 0.0;
                for (unsigned i = s0 + lane; i < e0; i += 64) {
                    double vd = (double)L.y2[i];      // own fresh writes: same CU, cached
                    s1 += vd; s2 += vd * vd;
                }
                #pragma unroll
                for (int off = 32; off > 0; off >>= 1) {
                    s1 += __shfl_xor(s1, off);
                    s2 += __shfl_xor(s2, off);
                }
                if (lane == 0) {
                    L.bS1[b * 8 + j] = s1;
                    L.bS2[b * 8 + j] = s2;
                    atomicAdd(&L.chS1[b >> 4], s1);   // device-scope, chunk totals
                    atomicAdd(&L.chS2[b >> 4], s2);
                }
            }
            __syncthreads();
        }
    }
    gbar(&L.ctrs[2]);   // publishes y2, bS1/bS2, fstart (chunk atomics already coherent)

    // ---- Ph7: redundant chunk scan + per-block 128-fine-bin exclusive prefix -> P1/P2 ----
    {
        double* d1 = (double*)SHB;                   // 256
        double* d2 = d1 + GRID;                      // 256 (4 KB total)
        double a1 = L.chS1[tid], a2 = L.chS2[tid];
        d1[tid] = a1; d2[tid] = a2;
        __syncthreads();
        for (int off = 1; off < GRID; off <<= 1) {   // Hillis-Steele inclusive
            double v1 = (tid >= off) ? d1[tid - off] : 0.0;
            double v2 = (tid >= off) ? d2[tid - off] : 0.0;
            __syncthreads();
            d1[tid] += v1; d2[tid] += v2;
            __syncthreads();
        }
        double base1 = (blk == 0) ? 0.0 : d1[blk - 1];
        double base2 = (blk == 0) ? 0.0 : d2[blk - 1];
        if (blk == 0 && tid == 0) {
            L.P1[NBF] = d1[GRID - 1];
            L.P2[NBF] = d2[GRID - 1];
            L.fstart[NBF] = (unsigned)n;
        }
        __syncthreads();
        // per-block prefix over its contiguous chunk of FPB fine bins
        double* a1s = (double*)SHB;
        double* a2s = a1s + FPB;
        int base = blk * FPB;
        double o1 = 0.0, o2 = 0.0;
        if (tid < FPB) {
            o1 = L.bS1[base + tid]; o2 = L.bS2[base + tid];
            a1s[tid] = o1; a2s[tid] = o2;
        }
        __syncthreads();
        for (int off = 1; off < FPB; off <<= 1) {
            double v1 = 0.0, v2 = 0.0;
            if (tid < FPB && tid >= off) { v1 = a1s[tid - off]; v2 = a2s[tid - off]; }
            __syncthreads();
            if (tid < FPB) { a1s[tid] += v1; a2s[tid] += v2; }
            __syncthreads();
        }
        if (tid < FPB) {
            L.P1[base + tid] = base1 + a1s[tid] - o1;   // exclusive
            L.P2[base + tid] = base2 + a2s[tid] - o2;
        }
    }
    gbar(&L.ctrs[3]);   // publishes P1/P2

    // ---- Ph8: analytic scorer, candidates stride-assigned; per-block argmin ----
    {
        double* sC  = (double*)SHC;
        double* s1v = sC + 16;
        double* s2v = s1v + 16;
        double bestS = 1.0e300; int bestI = 0x7fffffff;
        for (int cand = blk; cand < NCAND; cand += GRID) {
            float4 p = L.params[cand];
            int zi = (int)(0.0f - p.z);
            double sd = (double)p.x;
            __syncthreads();                          // protect sC reuse
            for (int j = wv; j < 15; j += 4) {
                double td = ((double)(j - zi) + 0.5) * sd;
                float tf = (float)td;
                int bf = bin_fine(tf, lo, invw);
                unsigned bb = L.fstart[bf], be = L.fstart[bf + 1];
                unsigned cc = 0; double t1 = 0.0, t2 = 0.0;
                for (unsigned i = bb + lane; i < be; i += 64) {
                    float v = L.y2[i];
                    if (v < tf) { cc++; double vd = (double)v; t1 += vd; t2 += vd * vd; }
                }
                #pragma unroll
                for (int off = 32; off > 0; off >>= 1) {
                    cc += __shfl_xor(cc, off);
                    t1 += __shfl_xor(t1, off);
                    t2 += __shfl_xor(t2, off);
                }
                if (lane == 0) {
                    sC[j]  = (double)bb + (double)cc;
                    s1v[j] = L.P1[bf] + t1;
                    s2v[j] = L.P2[bf] + t2;
                }
            }
            __syncthreads();
            if (tid == 0) {
                double prevC = 0.0, prev1 = 0.0, prev2 = 0.0, sc = 0.0;
                double nTot = (double)L.fstart[NBF];
                for (int j = 0; j <= 15; j++) {
                    double Cc, C1, C2;
                    if (j < 15) { Cc = sC[j]; C1 = s1v[j]; C2 = s2v[j]; }
                    else        { Cc = nTot; C1 = L.P1[NBF]; C2 = L.P2[NBF]; }
                    double ms = (double)(j - zi) * sd;
                    sc += (Cc - prevC) * ms * ms - 2.0 * ms * (C1 - prev1) + (C2 - prev2);
                    prevC = Cc; prev1 = C1; prev2 = C2;
                }
                if (sc < bestS) { bestS = sc; bestI = cand; }  // ascending cand keeps first-min
            }
        }
        if (tid == 0) { L.pbS[blk] = bestS; L.pbI[blk] = bestI; }
    }
    gbar(&L.ctrs[4]);   // publishes pbS/pbI

    // ---- Ph9 (block 0): lexicographic argmin over block partials ----
    if (blk == 0) {
        double* bsc = (double*)SHB;
        int*    bix = (int*)(SHB + sizeof(double) * GRID);
        bsc[tid] = L.pbS[tid]; bix[tid] = L.pbI[tid];
        __syncthreads();
        for (int s = 128; s > 0; s >>= 1) {
            if (tid < s) {
                double so = bsc[tid + s]; int io = bix[tid + s];
                if (so < bsc[tid] || (so == bsc[tid] && io < bix[tid])) { bsc[tid] = so; bix[tid] = io; }
            }
            __syncthreads();
        }
        if (tid == 0) {
            float bmin = L.mm[0], bmax = L.mm[1];
            if (bix[0] != 0x7fffffff) {
                float2 r = L.ranges[bix[0]];
                bmin = r.x; bmax = r.y;
            }
            out[0] = bmin; out[1] = bmax;
        }
    }
}

// ================= fallback path (round-1 proven) =================
__global__ __launch_bounds__(256) void k_params_fb(const float* __restrict__ x, int n4,
                                                   float4* __restrict__ params,
                                                   float2* __restrict__ ranges,
                                                   double* __restrict__ score,
                                                   float* __restrict__ mm) {
#pragma clang fp contract(off)
    __shared__ float smin[256], smax[256];
    const float4* x4 = (const float4*)x;
    float lmin = 3.0e38f, lmax = -3.0e38f;
    for (int i = threadIdx.x; i < n4; i += 256) {
        float4 v = x4[i];
        lmin = fminf(lmin, fminf(fminf(v.x, v.y), fminf(v.z, v.w)));
        lmax = fmaxf(lmax, fmaxf(fmaxf(v.x, v.y), fmaxf(v.z, v.w)));
    }
    smin[threadIdx.x] = lmin; smax[threadIdx.x] = lmax;
    __syncthreads();
    for (int s = 128; s > 0; s >>= 1) {
        if (threadIdx.x < s) {
            smin[threadIdx.x] = fminf(smin[threadIdx.x], smin[threadIdx.x + s]);
            smax[threadIdx.x] = fmaxf(smax[threadIdx.x], smax[threadIdx.x + s]);
        }
        __syncthreads();
    }
    float x_min = smin[0], x_max = smax[0];
    if (threadIdx.x == 0) { mm[0] = x_min; mm[1] = x_max; }
    float xrange = x_max - x_min;
    float step = xrange / 100.0f;
    for (int c = threadIdx.x; c < NCAND; c += 256) {
        int ii = c >> 4;
        int z  = c & 15;
        float fi = (float)(ii + 1);
        float tmp_max   = step * fi;
        float tmp_delta = tmp_max / 15.0f;
        float t = (float)z * tmp_delta;
        float new_min = fmaxf(-t, x_min);
        float new_max = fminf(tmp_max - t, x_max);
        float min_neg = fminf(new_min, 0.0f);
        float max_pos = fmaxf(new_max, 0.0f);
        float scale = fmaxf((max_pos - min_neg) / 15.0f, F32_EPS);
        float zp = 0.0f - rintf(min_neg / scale);
        zp = fminf(fmaxf(zp, 0.0f), 15.0f);
        float inv = (float)(1.0 / (double)scale);
        params[c] = make_float4(scale, inv, 0.0f - zp, 15.0f - zp);
        ranges[c] = make_float2(new_min, new_max);
        score[c]  = 0.0;
    }
}

__global__ __launch_bounds__(256) void k_score_bf(const float* __restrict__ x, int n4,
                                                  const float4* __restrict__ params,
                                                  double* __restrict__ score) {
    const int tid = blockIdx.x * 256 + threadIdx.x;
    const int T = gridDim.x * 256;
    const float4* x4 = (const float4*)x;
    float xs[16];
    #pragma unroll
    for (int k = 0; k < 4; k++) {
        int i4 = tid + k * T;
        float4 v;
        if (i4 < n4) v = x4[i4];
        else { v.x = 0.0f; v.y = 0.0f; v.z = 0.0f; v.w = 0.0f; }
        xs[4*k+0] = v.x; xs[4*k+1] = v.y; xs[4*k+2] = v.z; xs[4*k+3] = v.w;
    }
    int c = (int)((blockIdx.x * 37u) % NCAND);
    for (int k = 0; k < NCAND; k++) {
        float4 p = params[c];
        float s   = rfl_f(p.x);
        float inv = rfl_f(p.y);
        float lo  = rfl_f(p.z);
        float hi  = rfl_f(p.w);
        float acc = 0.0f;
        #pragma unroll
        for (int e = 0; e < 16; e++) {
            float r = rintf(xs[e] * inv);
            r = fminf(fmaxf(r, lo), hi);
            float d = fmaf(r, s, -xs[e]);
            acc = fmaf(d, d, acc);
        }
        #pragma unroll
        for (int off = 32; off > 0; off >>= 1)
            acc += __shfl_xor(acc, off);
        if ((threadIdx.x & 63) == 0)
            atomicAdd(&score[c], (double)acc);
        c++; if (c >= NCAND) c -= NCAND;
    }
}

__global__ void k_final_fb(const double* __restrict__ score,
                           const float2* __restrict__ ranges,
                           const float* __restrict__ mm,
                           float* __restrict__ out) {
    if (blockIdx.x == 0 && threadIdx.x == 0) {
        double best = 1.0e300;
        float bmin = mm[0], bmax = mm[1];
        for (int c = 0; c < NCAND; c++) {
            double sc = score[c];
            if (sc < best) { best = sc; bmin = ranges[c].x; bmax = ranges[c].y; }
        }
        out[0] = bmin;
        out[1] = bmax;
    }
}

extern "C" void kernel_launch(void* const* d_in, const int* in_sizes, int n_in,
                              void* d_out, int out_size, void* d_ws, size_t ws_size,
                              hipStream_t stream) {
    const float* x = (const float*)d_in[0];
    int n  = in_sizes[0];          // 4194304
    int n4 = n / 4;
    float* out = (float*)d_out;
    WSL L = make_ws((char*)d_ws, n);

    if (ws_size >= L.full_needed && (n % 4) == 0 && n4 >= GRID) {
        hipMemsetAsync(d_ws, 0, 64, stream);               // barrier counters only
        k_minmax_setup<<<GRID, BLK, 0, stream>>>(x, n4, (char*)d_ws, n);
        k_main<<<GRID, BLK, 0, stream>>>(x, n, n4, (char*)d_ws, out);
    } else if (ws_size >= L.small_needed) {
        k_params_fb<<<1, 256, 0, stream>>>(x, n4, L.params, L.ranges, L.scoreFB, L.mm);
        int blocks = ((n4 + 3) / 4 + 255) / 256;
        k_score_bf<<<blocks, 256, 0, stream>>>(x, n4, L.params, L.scoreFB);
        k_final_fb<<<1, 64, 0, stream>>>(L.scoreFB, L.ranges, L.mm, out);
    }
}